// Round 8
// baseline (517.739 us; speedup 1.0000x reference)
//
#include <hip/hip_runtime.h>
#include <cstddef>
#include <cstdint>

typedef unsigned short ushort_t;
typedef __attribute__((ext_vector_type(8))) short short8;
typedef __attribute__((ext_vector_type(4))) short short4v;
typedef __attribute__((ext_vector_type(4))) float f32x4;

__device__ __forceinline__ float bf2f(unsigned short u) {
  union { uint32_t i; float f; } x; x.i = ((uint32_t)u) << 16; return x.f;
}
__device__ __forceinline__ unsigned short f2bf(float f) {
  union { float f; uint32_t i; } x; x.f = f;
  uint32_t u = x.i;
  return (unsigned short)((u + 0x7fffu + ((u >> 16) & 1)) >> 16);
}
__device__ __forceinline__ void acc2(float ee, uint32_t wv, float& a, float& b) {
  a += ee * bf2f((unsigned short)(wv & 0xffffu));
  b += ee * bf2f((unsigned short)(wv >> 16));
}

// ---------------- CSR build ----------------
__global__ void count_kernel(const int* __restrict__ dst, int* __restrict__ cnt,
                             int E, int N) {
  int i = blockIdx.x * blockDim.x + threadIdx.x;
  if (i >= E + N) return;
  int d = (i < E) ? dst[i] : (i - E);   // self-loops appended
  atomicAdd(&cnt[d], 1);
}

__global__ void scan1_kernel(const int* __restrict__ cnt, int* __restrict__ exc,
                             int* __restrict__ psum, int N) {
  __shared__ int tmp[256];
  int tid = threadIdx.x;
  int i = blockIdx.x * 256 + tid;
  int v = (i < N) ? cnt[i] : 0;
  tmp[tid] = v;
  __syncthreads();
  for (int d = 1; d < 256; d <<= 1) {
    int t = (tid >= d) ? tmp[tid - d] : 0;
    __syncthreads();
    tmp[tid] += t;
    __syncthreads();
  }
  if (i < N) exc[i] = tmp[tid] - v;
  if (tid == 255) psum[blockIdx.x] = tmp[255];
}

__global__ void scan2_kernel(int* __restrict__ psum, int* __restrict__ offs,
                             int nb, int N) {
  __shared__ int tmp[256];
  int tid = threadIdx.x;
  int v = (tid < nb) ? psum[tid] : 0;
  tmp[tid] = v;
  __syncthreads();
  for (int d = 1; d < 256; d <<= 1) {
    int t = (tid >= d) ? tmp[tid - d] : 0;
    __syncthreads();
    tmp[tid] += t;
    __syncthreads();
  }
  if (tid < nb) psum[tid] = tmp[tid] - v;     // exclusive block offsets
  if (tid == 255) offs[N] = tmp[255];         // grand total = E + N
}

__global__ void scan3_kernel(const int* __restrict__ exc, const int* __restrict__ psum,
                             int* __restrict__ offs, int* __restrict__ fill, int N) {
  int i = blockIdx.x * blockDim.x + threadIdx.x;
  if (i >= N) return;
  int e = exc[i] + psum[i >> 8];
  offs[i] = e;
  fill[i] = e;
}

__global__ void fill_kernel(const int* __restrict__ src, const int* __restrict__ dst,
                            int* __restrict__ fill, int* __restrict__ srcs,
                            int E, int N) {
  int i = blockIdx.x * blockDim.x + threadIdx.x;
  if (i >= E + N) return;
  int s, d;
  if (i < E) { s = src[i]; d = dst[i]; } else { s = i - E; d = s; }
  int pos = atomicAdd(&fill[d], 1);
  srcs[pos] = s;
}

__global__ void starts_kernel(const int* __restrict__ batch, int* __restrict__ gstart,
                              int N, int G) {
  int n = blockIdx.x * blockDim.x + threadIdx.x;
  if (n >= N) return;
  if (n == 0) {
    int b0 = batch[0];
    for (int g = 0; g <= b0; ++g) gstart[g] = 0;
    int bl = batch[N - 1];
    for (int g = bl + 1; g <= G; ++g) gstart[g] = N;
  } else {
    int a = batch[n - 1], b = batch[n];
    for (int g = a + 1; g <= b; ++g) gstart[g] = n;
  }
}

// ---------------- fp32 -> bf16 conversions ----------------
__global__ void f2bf_kernel(const float* __restrict__ in, unsigned short* __restrict__ out,
                            int n4) {  // n4 = n/4
  int i = blockIdx.x * 256 + threadIdx.x;
  if (i >= n4) return;
  float4 v = *reinterpret_cast<const float4*>(in + (size_t)i * 4);
  unsigned short o[4] = {f2bf(v.x), f2bf(v.y), f2bf(v.z), f2bf(v.w)};
  *reinterpret_cast<uint2*>(out + (size_t)i * 4) = *reinterpret_cast<uint2*>(o);
}

// all three W [K][C] fp32 -> WT [C][K] bf16 in one launch
__global__ void wt3_kernel(const float* __restrict__ W1, const float* __restrict__ W2,
                           const float* __restrict__ W3,
                           unsigned short* __restrict__ WT1, unsigned short* __restrict__ WT2,
                           unsigned short* __restrict__ WT3) {
  int i = blockIdx.x * 256 + threadIdx.x;
  const float* W; unsigned short* WT; int K, C, j;
  if (i < 32768)       { W = W1; WT = WT1; K = 128; C = 256; j = i; }
  else if (i < 163840) { W = W2; WT = WT2; K = 256; C = 512; j = i - 32768; }
  else if (i < 294912) { W = W3; WT = WT3; K = 512; C = 256; j = i - 163840; }
  else return;
  int c = j / K, k = j - c * K;
  WT[j] = f2bf(W[(size_t)k * C + c]);
}

// ------- bf16 MFMA GEMM + fused al epilogue: C = A @ BT^T, als/ald = C·a_s/a_d -------
// 1-D grid, bijective XCD-chunked swizzle, y fastest within chunk (A-tile L2 reuse).
// HW = head width (COUT/8). Each head's cols lie inside one 128-col tile ->
// per-(row,head) al dot is block-exclusive: no atomics, deterministic.
template <int HW>
__global__ void __launch_bounds__(256)
gemm_al_kernel(const unsigned short* __restrict__ A, const unsigned short* __restrict__ BT,
               unsigned short* __restrict__ C, const float* __restrict__ a_s,
               const float* __restrict__ a_d, float* __restrict__ als,
               float* __restrict__ ald, int M, int K, int Nc, int yshift) {
  __shared__ unsigned short As[8192];   // [128 rows][64 bf16], XOR-swizzled content
  __shared__ unsigned short Bs[8192];
  int nwg = gridDim.x;
  int q = nwg >> 3, r = nwg & 7;
  int wg = blockIdx.x;
  int xcd = wg & 7, idx = wg >> 3;
  int swz = (xcd < r) ? (xcd * (q + 1) + idx)
                      : (r * (q + 1) + (xcd - r) * q + idx);
  int x = swz >> yshift, y = swz & ((1 << yshift) - 1);
  int m0 = x << 7, n0 = y << 7;

  int tid = threadIdx.x;
  int lane = tid & 63;
  int w = tid >> 6;
  int wm = w & 1, wn = w >> 1;
  f32x4 zero = {0.f, 0.f, 0.f, 0.f};
  f32x4 acc[4][4];
#pragma unroll
  for (int i = 0; i < 4; ++i)
#pragma unroll
    for (int j = 0; j < 4; ++j) acc[i][j] = zero;

  for (int k0 = 0; k0 < K; k0 += 64) {
    __syncthreads();  // previous tile's reads complete before overwrite
#pragma unroll
    for (int it = 0; it < 4; ++it) {
      int phys = it * 4096 + tid * 16;              // linear LDS byte dest
      int row = phys >> 7;                          // 128 B per row
      int col16 = ((phys >> 4) & 7) ^ (row & 7);    // inverse-swizzled source col
      int arow = m0 + row; arow = arow < M ? arow : M - 1;  // clamp
      const unsigned short* ga = A + (size_t)arow * K + k0 + col16 * 8;
      __builtin_amdgcn_global_load_lds(
          (const __attribute__((address_space(1))) void*)ga,
          (__attribute__((address_space(3))) void*)((char*)As + phys), 16, 0, 0);
      const unsigned short* gb = BT + (size_t)(n0 + row) * K + k0 + col16 * 8;
      __builtin_amdgcn_global_load_lds(
          (const __attribute__((address_space(1))) void*)gb,
          (__attribute__((address_space(3))) void*)((char*)Bs + phys), 16, 0, 0);
    }
    asm volatile("s_waitcnt vmcnt(0)" ::: "memory");
    __syncthreads();
#pragma unroll
    for (int ks = 0; ks < 2; ++ks) {
      short8 af[4], bfr[4];
#pragma unroll
      for (int m = 0; m < 4; ++m) {
        int row = wm * 64 + m * 16 + (lane & 15);
        int colb = ks * 64 + (lane >> 4) * 16;
        int phys = (row << 7) + (colb ^ ((row & 7) << 4));
        af[m] = *(const short8*)((const char*)As + phys);
      }
#pragma unroll
      for (int n = 0; n < 4; ++n) {
        int row = wn * 64 + n * 16 + (lane & 15);
        int colb = ks * 64 + (lane >> 4) * 16;
        int phys = (row << 7) + (colb ^ ((row & 7) << 4));
        bfr[n] = *(const short8*)((const char*)Bs + phys);
      }
#pragma unroll
      for (int m = 0; m < 4; ++m)
#pragma unroll
        for (int n = 0; n < 4; ++n)
          acc[m][n] = __builtin_amdgcn_mfma_f32_16x16x32_bf16(af[m], bfr[n], acc[m][n], 0, 0, 0);
    }
  }

  // ---- C store + fused al partial dots ----
  int hb = (n0 + wn * 64) / HW;         // base head of this wave's 64-col span
#pragma unroll
  for (int m = 0; m < 4; ++m) {
#pragma unroll
    for (int r2 = 0; r2 < 4; ++r2) {
      int row = m0 + wm * 64 + m * 16 + (lane >> 4) * 4 + r2;
      bool ok = row < M;
      float s0 = 0.f, d0 = 0.f, s1 = 0.f, d1 = 0.f;
#pragma unroll
      for (int n = 0; n < 4; ++n) {
        int col = n0 + wn * 64 + n * 16 + (lane & 15);
        float v = acc[m][n][r2];
        if (ok) C[(size_t)row * Nc + col] = f2bf(v);
        float ws = a_s[col], wd = a_d[col];
        if (HW == 64 || n < 2) { s0 += v * ws; d0 += v * wd; }
        else                   { s1 += v * ws; d1 += v * wd; }
      }
#pragma unroll
      for (int o = 1; o <= 8; o <<= 1) {
        s0 += __shfl_xor(s0, o); d0 += __shfl_xor(d0, o);
        if (HW == 32) { s1 += __shfl_xor(s1, o); d1 += __shfl_xor(d1, o); }
      }
      if ((lane & 15) == 0 && ok) {
        als[(size_t)row * 8 + hb] = s0;
        ald[(size_t)row * 8 + hb] = d0;
        if (HW == 32) {
          als[(size_t)row * 8 + hb + 1] = s1;
          ald[(size_t)row * 8 + hb + 1] = d1;
        }
      }
    }
  }
}

// ------- agg v4: one wave per node; wave-private LDS; 16B gathers; gate fusion -------
#define LEAKY(x) ((x) >= 0.f ? (x) : 0.2f * (x))
template <int COUT, bool GATE>
__global__ void __launch_bounds__(256)
agg4_kernel(const unsigned short* __restrict__ hpre, const float* __restrict__ als,
            const float* __restrict__ ald, const int* __restrict__ srcs,
            const int* __restrict__ offs, const float* __restrict__ bias,
            const float* __restrict__ gamma, const float* __restrict__ beta,
            const float* __restrict__ mean, const float* __restrict__ var,
            unsigned short* __restrict__ hout,
            const float* __restrict__ gw, const float* __restrict__ gb,
            float* __restrict__ gate, int N) {
  constexpr int VEC = COUT / 64;        // channels per lane: 4 or 8
  constexpr int CAP = 128;
  constexpr int EPAD = 132;
  __shared__ float ehs[4][8][EPAD];
  __shared__ int srcsS[4][CAP];
  int tid = threadIdx.x;
  int w = tid >> 6, l = tid & 63;
  int n = blockIdx.x * 4 + w;
  if (n >= N) return;                   // whole wave exits; no block-level syncs used
  int e0 = offs[n];
  int deg = offs[n + 1] - e0;
  int mcap = deg < CAP ? deg : CAP;
  int hdA = l & 7;                      // head for weight phases
  int eb = l >> 3;                      // edge sub-lane for weight phases
  float aldv = ald[((size_t)n << 3) + hdA];

  // stage srcs into wave-private LDS
  for (int e = l; e < mcap; e += 64) srcsS[w][e] = srcs[e0 + e];

  // phase A: logits -> LDS
  for (int e = eb; e < mcap; e += 8) {
    int s = srcsS[w][e];
    float xx = als[((size_t)(uint32_t)s << 3) + hdA] + aldv;
    ehs[w][hdA][e] = LEAKY(xx);
  }
  // phase B: per-head max (lanes sharing hdA differ in bits 3..5)
  float mx = -1e30f;
  for (int e = eb; e < mcap; e += 8) mx = fmaxf(mx, ehs[w][hdA][e]);
  for (int e = CAP + eb; e < deg; e += 8) {         // overflow (rare)
    int s = srcs[e0 + e];
    mx = fmaxf(mx, LEAKY(als[((size_t)(uint32_t)s << 3) + hdA] + aldv));
  }
  mx = fmaxf(mx, __shfl_xor(mx, 8));
  mx = fmaxf(mx, __shfl_xor(mx, 16));
  mx = fmaxf(mx, __shfl_xor(mx, 32));
  // phase B2: exp in place + denominator
  float dp = 0.f;
  for (int e = eb; e < mcap; e += 8) {
    float ee = __expf(ehs[w][hdA][e] - mx);
    ehs[w][hdA][e] = ee;
    dp += ee;
  }
  for (int e = CAP + eb; e < deg; e += 8) {         // overflow (rare)
    int s = srcs[e0 + e];
    dp += __expf(LEAKY(als[((size_t)(uint32_t)s << 3) + hdA] + aldv) - mx);
  }
  dp += __shfl_xor(dp, 8);
  dp += __shfl_xor(dp, 16);
  dp += __shfl_xor(dp, 32);
  float dinv = 1.f / (dp + 1e-16f);

  // remap to phase-C head (lane owns channels [VEC*l, VEC*l+VEC) -> head = l>>3)
  int hdC = l >> 3;
  float dinvC = __shfl(dinv, hdC);
  float mxC = __shfl(mx, hdC);
  float aldC = __shfl(aldv, hdC);
  const float* eerow = ehs[w][hdC];

  // phase C: wide row gather + weighted accumulate
  float num[VEC] = {};
  int e = 0;
  if (VEC == 4) {
    const uint2* hp = reinterpret_cast<const uint2*>(hpre);  // row = 64 uint2
    // 8-deep batch: all loads issued before accumulation (counted-vmcnt overlap)
    for (; e + 8 <= mcap; e += 8) {
      uint2 wv[8];
#pragma unroll
      for (int j = 0; j < 8; ++j) {
        int s = srcsS[w][e + j];
        wv[j] = hp[((size_t)(uint32_t)s << 6) + l];
      }
#pragma unroll
      for (int j = 0; j < 8; ++j) {
        float ee = eerow[e + j];
        acc2(ee, wv[j].x, num[0], num[1]); acc2(ee, wv[j].y, num[2], num[3]);
      }
    }
    for (; e + 4 <= mcap; e += 4) {
      uint2 wv[4];
#pragma unroll
      for (int j = 0; j < 4; ++j) {
        int s = srcsS[w][e + j];
        wv[j] = hp[((size_t)(uint32_t)s << 6) + l];
      }
#pragma unroll
      for (int j = 0; j < 4; ++j) {
        float ee = eerow[e + j];
        acc2(ee, wv[j].x, num[0], num[1]); acc2(ee, wv[j].y, num[2], num[3]);
      }
    }
    for (; e < mcap; ++e) {
      int s = srcsS[w][e];
      uint2 w0 = hp[((size_t)(uint32_t)s << 6) + l];
      float ee0 = eerow[e];
      acc2(ee0, w0.x, num[0], num[1]); acc2(ee0, w0.y, num[2], num[3]);
    }
    for (; e < deg; ++e) {  // overflow (rare)
      int s = srcs[e0 + e];
      float ee0 = __expf(LEAKY(als[((size_t)(uint32_t)s << 3) + hdC] + aldC) - mxC);
      uint2 w0 = hp[((size_t)(uint32_t)s << 6) + l];
      acc2(ee0, w0.x, num[0], num[1]); acc2(ee0, w0.y, num[2], num[3]);
    }
  } else {
    const uint4* hp = reinterpret_cast<const uint4*>(hpre);  // row = 64 uint4
    for (; e + 4 <= mcap; e += 4) {
      int s0 = srcsS[w][e], s1 = srcsS[w][e + 1];
      int s2 = srcsS[w][e + 2], s3 = srcsS[w][e + 3];
      uint4 w0 = hp[((size_t)(uint32_t)s0 << 6) + l];
      uint4 w1 = hp[((size_t)(uint32_t)s1 << 6) + l];
      uint4 w2 = hp[((size_t)(uint32_t)s2 << 6) + l];
      uint4 w3 = hp[((size_t)(uint32_t)s3 << 6) + l];
      float ee0 = eerow[e], ee1 = eerow[e + 1], ee2 = eerow[e + 2], ee3 = eerow[e + 3];
      acc2(ee0, w0.x, num[0], num[1]); acc2(ee0, w0.y, num[2], num[3]);
      acc2(ee0, w0.z, num[4], num[5]); acc2(ee0, w0.w, num[6], num[7]);
      acc2(ee1, w1.x, num[0], num[1]); acc2(ee1, w1.y, num[2], num[3]);
      acc2(ee1, w1.z, num[4], num[5]); acc2(ee1, w1.w, num[6], num[7]);
      acc2(ee2, w2.x, num[0], num[1]); acc2(ee2, w2.y, num[2], num[3]);
      acc2(ee2, w2.z, num[4], num[5]); acc2(ee2, w2.w, num[6], num[7]);
      acc2(ee3, w3.x, num[0], num[1]); acc2(ee3, w3.y, num[2], num[3]);
      acc2(ee3, w3.z, num[4], num[5]); acc2(ee3, w3.w, num[6], num[7]);
    }
    for (; e < mcap; ++e) {
      int s = srcsS[w][e];
      uint4 w0 = hp[((size_t)(uint32_t)s << 6) + l];
      float ee0 = eerow[e];
      acc2(ee0, w0.x, num[0], num[1]); acc2(ee0, w0.y, num[2], num[3]);
      acc2(ee0, w0.z, num[4], num[5]); acc2(ee0, w0.w, num[6], num[7]);
    }
    for (; e < deg; ++e) {  // overflow (rare)
      int s = srcs[e0 + e];
      float ee0 = __expf(LEAKY(als[((size_t)(uint32_t)s << 3) + hdC] + aldC) - mxC);
      uint4 w0 = hp[((size_t)(uint32_t)s << 6) + l];
      acc2(ee0, w0.x, num[0], num[1]); acc2(ee0, w0.y, num[2], num[3]);
      acc2(ee0, w0.z, num[4], num[5]); acc2(ee0, w0.w, num[6], num[7]);
    }
  }

  // epilogue: bias + BN + ReLU (+ optional fused gate dot)
  unsigned short o[VEC];
  float gp = 0.f;
#pragma unroll
  for (int v = 0; v < VEC; ++v) {
    int c = VEC * l + v;
    float xo = num[v] * dinvC + bias[c];
    xo = (xo - mean[c]) * rsqrtf(var[c] + 1e-5f) * gamma[c] + beta[c];
    xo = fmaxf(xo, 0.f);
    o[v] = f2bf(xo);
    if (GATE) gp += xo * gw[c];
  }
  if (VEC == 4)
    *reinterpret_cast<uint2*>(&hout[(size_t)n * COUT + VEC * l]) = *reinterpret_cast<uint2*>(o);
  else
    *reinterpret_cast<uint4*>(&hout[(size_t)n * COUT + VEC * l]) = *reinterpret_cast<uint4*>(o);
  if (GATE) {
    gp += __shfl_xor(gp, 1);
    gp += __shfl_xor(gp, 2);
    gp += __shfl_xor(gp, 4);
    gp += __shfl_xor(gp, 8);
    gp += __shfl_xor(gp, 16);
    gp += __shfl_xor(gp, 32);
    if (l == 0) gate[n] = gp + gb[0];
  }
}

// ---------------- pooling ----------------
__global__ void __launch_bounds__(256)
poolmax_kernel(const float* __restrict__ gate, const int* __restrict__ gstart,
               float* __restrict__ gmax, float* __restrict__ ginv) {
  int g = blockIdx.x;
  int tid = threadIdx.x;
  int n0 = gstart[g], n1 = gstart[g + 1];
  __shared__ float red[4];
  float mx = -1e30f;
  for (int n = n0 + tid; n < n1; n += 256) mx = fmaxf(mx, gate[n]);
#pragma unroll
  for (int o = 32; o >= 1; o >>= 1) mx = fmaxf(mx, __shfl_xor(mx, o));
  if ((tid & 63) == 0) red[tid >> 6] = mx;
  __syncthreads();
  mx = fmaxf(fmaxf(red[0], red[1]), fmaxf(red[2], red[3]));
  __syncthreads();
  float sm = 0.f;
  for (int n = n0 + tid; n < n1; n += 256) sm += __expf(gate[n] - mx);
#pragma unroll
  for (int o = 32; o >= 1; o >>= 1) sm += __shfl_xor(sm, o);
  if ((tid & 63) == 0) red[tid >> 6] = sm;
  __syncthreads();
  if (tid == 0) {
    sm = red[0] + red[1] + red[2] + red[3];
    gmax[g] = mx;
    ginv[g] = 1.f / (sm + 1e-16f);
  }
}

__global__ void __launch_bounds__(256)
poolsum_kernel(const float* __restrict__ gate, const unsigned short* __restrict__ h3,
               const int* __restrict__ batch, const float* __restrict__ gmax,
               const float* __restrict__ ginv, float* __restrict__ pooled, int N) {
  int tid = threadIdx.x;                 // channel 0..255
  int nbase = blockIdx.x * 64;
  float acc = 0.f;
  int cur = batch[nbase];
  for (int i = 0; i < 64; ++i) {
    int n = nbase + i;
    if (n >= N) break;
    int b = batch[n];
    if (b != cur) {
      atomicAdd(&pooled[cur * 256 + tid], acc);
      acc = 0.f;
      cur = b;
    }
    float w = __expf(gate[n] - gmax[b]) * ginv[b];
    acc += w * bf2f(h3[(size_t)n * 256 + tid]);
  }
  atomicAdd(&pooled[cur * 256 + tid], acc);
}

__global__ void __launch_bounds__(64)
head_kernel(const float* __restrict__ pooled, const float* __restrict__ f1w,
            const float* __restrict__ f1b, const float* __restrict__ f2w,
            const float* __restrict__ f2b, float* __restrict__ out) {
  int g = blockIdx.x;
  int l = threadIdx.x;  // 64 lanes
  float p[4];
#pragma unroll
  for (int v = 0; v < 4; ++v) p[v] = pooled[g * 256 + l * 4 + v];
  float acc = 0.f;
#pragma unroll
  for (int j = 0; j < 16; ++j) {
    float s = 0.f;
#pragma unroll
    for (int v = 0; v < 4; ++v) s += p[v] * f1w[(l * 4 + v) * 16 + j];
#pragma unroll
    for (int o = 32; o >= 1; o >>= 1) s += __shfl_xor(s, o);
    float hj = fmaxf(s + f1b[j], 0.f);
    acc += hj * f2w[j];
  }
  if (l == 0) out[g] = acc + f2b[0];
}

// ---------------- launch ----------------
extern "C" void kernel_launch(void* const* d_in, const int* in_sizes, int n_in,
                              void* d_out, int out_size, void* d_ws, size_t ws_size,
                              hipStream_t stream) {
  const float* x    = (const float*)d_in[0];
  const int*   ei   = (const int*)d_in[1];
  const int*   batch= (const int*)d_in[2];
  const float* W1   = (const float*)d_in[3];
  const float* a1s  = (const float*)d_in[4];
  const float* a1d  = (const float*)d_in[5];
  const float* b1   = (const float*)d_in[6];
  const float* g1   = (const float*)d_in[7];
  const float* be1  = (const float*)d_in[8];
  const float* m1   = (const float*)d_in[9];
  const float* v1   = (const float*)d_in[10];
  const float* W2   = (const float*)d_in[11];
  const float* a2s  = (const float*)d_in[12];
  const float* a2d  = (const float*)d_in[13];
  const float* b2   = (const float*)d_in[14];
  const float* g2   = (const float*)d_in[15];
  const float* be2  = (const float*)d_in[16];
  const float* m2   = (const float*)d_in[17];
  const float* v2   = (const float*)d_in[18];
  const float* W3   = (const float*)d_in[19];
  const float* a3s  = (const float*)d_in[20];
  const float* a3d  = (const float*)d_in[21];
  const float* b3   = (const float*)d_in[22];
  const float* g3   = (const float*)d_in[23];
  const float* be3  = (const float*)d_in[24];
  const float* m3   = (const float*)d_in[25];
  const float* v3   = (const float*)d_in[26];
  const float* gw   = (const float*)d_in[27];
  const float* gb   = (const float*)d_in[28];
  const float* f1w  = (const float*)d_in[29];
  const float* f1b  = (const float*)d_in[30];
  const float* f2w  = (const float*)d_in[31];
  const float* f2b  = (const float*)d_in[32];

  int N = in_sizes[2];        // 50000
  int E = in_sizes[1] / 2;    // 800000
  const int* esrc = ei;
  const int* edst = ei + E;

  char* ws = (char*)d_ws;
  size_t off = 0;
  auto take = [&](size_t bytes) -> void* {
    void* p = ws + off;
    off += (bytes + 255) & ~(size_t)255;
    return p;
  };
  unsigned short* XBF  = (unsigned short*)take((size_t)N * 128 * 2);
  unsigned short* WT1  = (unsigned short*)take((size_t)256 * 128 * 2);
  unsigned short* WT2  = (unsigned short*)take((size_t)512 * 256 * 2);
  unsigned short* WT3  = (unsigned short*)take((size_t)256 * 512 * 2);
  unsigned short* HPRE = (unsigned short*)take((size_t)N * 512 * 2);
  unsigned short* HB   = (unsigned short*)take((size_t)N * 512 * 2);
  float* ALS   = (float*)take((size_t)N * 8 * 4);
  float* ALD   = (float*)take((size_t)N * 8 * 4);
  int*   CNT   = (int*)take((size_t)N * 4);
  int*   OFFS  = (int*)take((size_t)(N + 1) * 4);
  int*   FILL  = (int*)take((size_t)N * 4);
  int*   EXC   = (int*)take((size_t)N * 4);
  int*   PSUM  = (int*)take(256 * 4);
  int*   SRCS  = (int*)take((size_t)(E + N) * 4);
  float* GATE  = (float*)take((size_t)N * 4);
  int*   GST   = (int*)take(65 * 4);
  float* POOLED= (float*)take(64 * 256 * 4);
  float* GMAX  = (float*)take(64 * 4);
  float* GINV  = (float*)take(64 * 4);
  (void)ws_size; (void)n_in; (void)out_size;

  // ---- conversions + CSR build ----
  f2bf_kernel<<<(N * 128 / 4 + 255) / 256, 256, 0, stream>>>(x, XBF, N * 128 / 4);
  wt3_kernel<<<(294912 + 255) / 256, 256, 0, stream>>>(W1, W2, W3, WT1, WT2, WT3);

  hipMemsetAsync(CNT, 0, (size_t)N * 4, stream);
  hipMemsetAsync(POOLED, 0, 64 * 256 * 4, stream);
  int tE = E + N;
  count_kernel<<<(tE + 255) / 256, 256, 0, stream>>>(edst, CNT, E, N);
  int nb = (N + 255) / 256;
  scan1_kernel<<<nb, 256, 0, stream>>>(CNT, EXC, PSUM, N);
  scan2_kernel<<<1, 256, 0, stream>>>(PSUM, OFFS, nb, N);
  scan3_kernel<<<nb, 256, 0, stream>>>(EXC, PSUM, OFFS, FILL, N);
  fill_kernel<<<(tE + 255) / 256, 256, 0, stream>>>(esrc, edst, FILL, SRCS, E, N);
  starts_kernel<<<(N + 255) / 256, 256, 0, stream>>>(batch, GST, N, 64);

  int mgrid = (N + 127) / 128;
  int agrid = (N + 3) / 4;

  // ---- layer 1: 128 -> 8x32 (head width 32) ----
  {
    gemm_al_kernel<32><<<mgrid * 2, 256, 0, stream>>>(XBF, WT1, HPRE, a1s, a1d,
                                                      ALS, ALD, N, 128, 256, 1);
    agg4_kernel<256, false><<<agrid, 256, 0, stream>>>(HPRE, ALS, ALD, SRCS, OFFS,
                                                       b1, g1, be1, m1, v1, HB,
                                                       nullptr, nullptr, nullptr, N);
  }
  // ---- layer 2: 256 -> 8x64 (head width 64) ----
  {
    gemm_al_kernel<64><<<mgrid * 4, 256, 0, stream>>>(HB, WT2, HPRE, a2s, a2d,
                                                      ALS, ALD, N, 256, 512, 2);
    agg4_kernel<512, false><<<agrid, 256, 0, stream>>>(HPRE, ALS, ALD, SRCS, OFFS,
                                                       b2, g2, be2, m2, v2, HB,
                                                       nullptr, nullptr, nullptr, N);
  }
  // ---- layer 3: 512 -> 8x32 (head width 32), gate fused ----
  {
    gemm_al_kernel<32><<<mgrid * 2, 256, 0, stream>>>(HB, WT3, HPRE, a3s, a3d,
                                                      ALS, ALD, N, 512, 256, 1);
    agg4_kernel<256, true><<<agrid, 256, 0, stream>>>(HPRE, ALS, ALD, SRCS, OFFS,
                                                      b3, g3, be3, m3, v3, HB,
                                                      gw, gb, GATE, N);
  }

  // ---- global attention pooling + MLP head ----
  poolmax_kernel<<<64, 256, 0, stream>>>(GATE, GST, GMAX, GINV);
  poolsum_kernel<<<(N + 63) / 64, 256, 0, stream>>>(GATE, HB, batch, GMAX, GINV, POOLED, N);
  head_kernel<<<64, 64, 0, stream>>>(POOLED, f1w, f1b, f2w, f2b, (float*)d_out);
}

// Round 9
// 497.337 us; speedup vs baseline: 1.0410x; 1.0410x over previous
//
#include <hip/hip_runtime.h>
#include <cstddef>
#include <cstdint>

typedef unsigned short ushort_t;
typedef __attribute__((ext_vector_type(8))) short short8;
typedef __attribute__((ext_vector_type(4))) short short4v;
typedef __attribute__((ext_vector_type(4))) float f32x4;

__device__ __forceinline__ float bf2f(unsigned short u) {
  union { uint32_t i; float f; } x; x.i = ((uint32_t)u) << 16; return x.f;
}
__device__ __forceinline__ unsigned short f2bf(float f) {
  union { float f; uint32_t i; } x; x.f = f;
  uint32_t u = x.i;
  return (unsigned short)((u + 0x7fffu + ((u >> 16) & 1)) >> 16);
}
__device__ __forceinline__ void acc2(float ee, uint32_t wv, float& a, float& b) {
  a += ee * bf2f((unsigned short)(wv & 0xffffu));
  b += ee * bf2f((unsigned short)(wv >> 16));
}

// ---------------- CSR build ----------------
__global__ void count_kernel(const int* __restrict__ dst, int* __restrict__ cnt,
                             int E, int N) {
  int i = blockIdx.x * blockDim.x + threadIdx.x;
  if (i >= E + N) return;
  int d = (i < E) ? dst[i] : (i - E);   // self-loops appended
  atomicAdd(&cnt[d], 1);
}

__global__ void scan1_kernel(const int* __restrict__ cnt, int* __restrict__ exc,
                             int* __restrict__ psum, int N) {
  __shared__ int tmp[256];
  int tid = threadIdx.x;
  int i = blockIdx.x * 256 + tid;
  int v = (i < N) ? cnt[i] : 0;
  tmp[tid] = v;
  __syncthreads();
  for (int d = 1; d < 256; d <<= 1) {
    int t = (tid >= d) ? tmp[tid - d] : 0;
    __syncthreads();
    tmp[tid] += t;
    __syncthreads();
  }
  if (i < N) exc[i] = tmp[tid] - v;
  if (tid == 255) psum[blockIdx.x] = tmp[255];
}

__global__ void scan2_kernel(int* __restrict__ psum, int* __restrict__ offs,
                             int nb, int N) {
  __shared__ int tmp[256];
  int tid = threadIdx.x;
  int v = (tid < nb) ? psum[tid] : 0;
  tmp[tid] = v;
  __syncthreads();
  for (int d = 1; d < 256; d <<= 1) {
    int t = (tid >= d) ? tmp[tid - d] : 0;
    __syncthreads();
    tmp[tid] += t;
    __syncthreads();
  }
  if (tid < nb) psum[tid] = tmp[tid] - v;     // exclusive block offsets
  if (tid == 255) offs[N] = tmp[255];         // grand total = E + N
}

__global__ void scan3_kernel(const int* __restrict__ exc, const int* __restrict__ psum,
                             int* __restrict__ offs, int* __restrict__ fill, int N) {
  int i = blockIdx.x * blockDim.x + threadIdx.x;
  if (i >= N) return;
  int e = exc[i] + psum[i >> 8];
  offs[i] = e;
  fill[i] = e;
}

__global__ void fill_kernel(const int* __restrict__ src, const int* __restrict__ dst,
                            int* __restrict__ fill, int* __restrict__ srcs,
                            int E, int N) {
  int i = blockIdx.x * blockDim.x + threadIdx.x;
  if (i >= E + N) return;
  int s, d;
  if (i < E) { s = src[i]; d = dst[i]; } else { s = i - E; d = s; }
  int pos = atomicAdd(&fill[d], 1);
  srcs[pos] = s;
}

__global__ void starts_kernel(const int* __restrict__ batch, int* __restrict__ gstart,
                              int N, int G) {
  int n = blockIdx.x * blockDim.x + threadIdx.x;
  if (n >= N) return;
  if (n == 0) {
    int b0 = batch[0];
    for (int g = 0; g <= b0; ++g) gstart[g] = 0;
    int bl = batch[N - 1];
    for (int g = bl + 1; g <= G; ++g) gstart[g] = N;
  } else {
    int a = batch[n - 1], b = batch[n];
    for (int g = a + 1; g <= b; ++g) gstart[g] = n;
  }
}

// ---------------- fp32 -> bf16 conversions ----------------
__global__ void f2bf_kernel(const float* __restrict__ in, unsigned short* __restrict__ out,
                            int n4) {  // n4 = n/4
  int i = blockIdx.x * 256 + threadIdx.x;
  if (i >= n4) return;
  float4 v = *reinterpret_cast<const float4*>(in + (size_t)i * 4);
  unsigned short o[4] = {f2bf(v.x), f2bf(v.y), f2bf(v.z), f2bf(v.w)};
  *reinterpret_cast<uint2*>(out + (size_t)i * 4) = *reinterpret_cast<uint2*>(o);
}

// all three W [K][C] fp32 -> WT [C][K] bf16 in one launch
__global__ void wt3_kernel(const float* __restrict__ W1, const float* __restrict__ W2,
                           const float* __restrict__ W3,
                           unsigned short* __restrict__ WT1, unsigned short* __restrict__ WT2,
                           unsigned short* __restrict__ WT3) {
  int i = blockIdx.x * 256 + threadIdx.x;
  const float* W; unsigned short* WT; int K, C, j;
  if (i < 32768)       { W = W1; WT = WT1; K = 128; C = 256; j = i; }
  else if (i < 163840) { W = W2; WT = WT2; K = 256; C = 512; j = i - 32768; }
  else if (i < 294912) { W = W3; WT = WT3; K = 512; C = 256; j = i - 163840; }
  else return;
  int c = j / K, k = j - c * K;
  WT[j] = f2bf(W[(size_t)k * C + c]);
}

// ---------------- bf16 MFMA GEMM: C[M,Nc] = A[M,K] @ BT[Nc,K]^T ----------------
// 1-D grid, bijective XCD-chunked swizzle, y fastest within chunk (A-tile L2 reuse).
__global__ void __launch_bounds__(256)
gemm_bf16(const unsigned short* __restrict__ A, const unsigned short* __restrict__ BT,
          unsigned short* __restrict__ C, int M, int K, int Nc, int yshift) {
  __shared__ unsigned short As[8192];   // [128 rows][64 bf16], XOR-swizzled content
  __shared__ unsigned short Bs[8192];
  int nwg = gridDim.x;
  int q = nwg >> 3, r = nwg & 7;
  int wg = blockIdx.x;
  int xcd = wg & 7, idx = wg >> 3;
  int swz = (xcd < r) ? (xcd * (q + 1) + idx)
                      : (r * (q + 1) + (xcd - r) * q + idx);
  int x = swz >> yshift, y = swz & ((1 << yshift) - 1);
  int m0 = x << 7, n0 = y << 7;

  int tid = threadIdx.x;
  int lane = tid & 63;
  int w = tid >> 6;
  int wm = w & 1, wn = w >> 1;
  f32x4 zero = {0.f, 0.f, 0.f, 0.f};
  f32x4 acc[4][4];
#pragma unroll
  for (int i = 0; i < 4; ++i)
#pragma unroll
    for (int j = 0; j < 4; ++j) acc[i][j] = zero;

  for (int k0 = 0; k0 < K; k0 += 64) {
    __syncthreads();  // previous tile's reads complete before overwrite
#pragma unroll
    for (int it = 0; it < 4; ++it) {
      int phys = it * 4096 + tid * 16;              // linear LDS byte dest
      int row = phys >> 7;                          // 128 B per row
      int col16 = ((phys >> 4) & 7) ^ (row & 7);    // inverse-swizzled source col
      int arow = m0 + row; arow = arow < M ? arow : M - 1;  // clamp
      const unsigned short* ga = A + (size_t)arow * K + k0 + col16 * 8;
      __builtin_amdgcn_global_load_lds(
          (const __attribute__((address_space(1))) void*)ga,
          (__attribute__((address_space(3))) void*)((char*)As + phys), 16, 0, 0);
      const unsigned short* gb = BT + (size_t)(n0 + row) * K + k0 + col16 * 8;
      __builtin_amdgcn_global_load_lds(
          (const __attribute__((address_space(1))) void*)gb,
          (__attribute__((address_space(3))) void*)((char*)Bs + phys), 16, 0, 0);
    }
    asm volatile("s_waitcnt vmcnt(0)" ::: "memory");
    __syncthreads();
#pragma unroll
    for (int ks = 0; ks < 2; ++ks) {
      short8 af[4], bfr[4];
#pragma unroll
      for (int m = 0; m < 4; ++m) {
        int row = wm * 64 + m * 16 + (lane & 15);
        int colb = ks * 64 + (lane >> 4) * 16;
        int phys = (row << 7) + (colb ^ ((row & 7) << 4));
        af[m] = *(const short8*)((const char*)As + phys);
      }
#pragma unroll
      for (int n = 0; n < 4; ++n) {
        int row = wn * 64 + n * 16 + (lane & 15);
        int colb = ks * 64 + (lane >> 4) * 16;
        int phys = (row << 7) + (colb ^ ((row & 7) << 4));
        bfr[n] = *(const short8*)((const char*)Bs + phys);
      }
#pragma unroll
      for (int m = 0; m < 4; ++m)
#pragma unroll
        for (int n = 0; n < 4; ++n)
          acc[m][n] = __builtin_amdgcn_mfma_f32_16x16x32_bf16(af[m], bfr[n], acc[m][n], 0, 0, 0);
    }
  }
#pragma unroll
  for (int m = 0; m < 4; ++m) {
#pragma unroll
    for (int r2 = 0; r2 < 4; ++r2) {
      int row = m0 + wm * 64 + m * 16 + (lane >> 4) * 4 + r2;
      if (row < M) {
#pragma unroll
        for (int n = 0; n < 4; ++n) {
          int col = n0 + wn * 64 + n * 16 + (lane & 15);
          C[(size_t)row * Nc + col] = f2bf(acc[m][n][r2]);
        }
      }
    }
  }
}

// ------------- per-node attention logits, one wave per row, wide loads -------------
template <int COUT>
__global__ void __launch_bounds__(256)
al2_kernel(const unsigned short* __restrict__ hpre, const float* __restrict__ a_s,
           const float* __restrict__ a_d, float* __restrict__ als,
           float* __restrict__ ald, int N) {
  constexpr int VEC = COUT / 64;        // channels per lane: 4 or 8
  int wv = threadIdx.x >> 6;
  int lane = threadIdx.x & 63;
  int n = blockIdx.x * 4 + wv;
  if (n >= N) return;
  const unsigned short* hp = hpre + (size_t)n * COUT + VEC * lane;
  unsigned short h[VEC];
  if (VEC == 4) *reinterpret_cast<short4v*>(h) = *reinterpret_cast<const short4v*>(hp);
  else          *reinterpret_cast<short8*>(h) = *reinterpret_cast<const short8*>(hp);
  float vs = 0.f, vd = 0.f;
#pragma unroll
  for (int v = 0; v < VEC; ++v) {
    float f = bf2f(h[v]);
    vs += f * a_s[VEC * lane + v];
    vd += f * a_d[VEC * lane + v];
  }
  vs += __shfl_xor(vs, 1); vd += __shfl_xor(vd, 1);
  vs += __shfl_xor(vs, 2); vd += __shfl_xor(vd, 2);
  vs += __shfl_xor(vs, 4); vd += __shfl_xor(vd, 4);
  if ((lane & 7) == 0) {
    int hd = lane >> 3;
    als[(size_t)n * 8 + hd] = vs;
    ald[(size_t)n * 8 + hd] = vd;
  }
}

// ------- agg v4: one wave per node; wave-private LDS; 16B gathers; gate fusion -------
#define LEAKY(x) ((x) >= 0.f ? (x) : 0.2f * (x))
template <int COUT, bool GATE>
__global__ void __launch_bounds__(256)
agg4_kernel(const unsigned short* __restrict__ hpre, const float* __restrict__ als,
            const float* __restrict__ ald, const int* __restrict__ srcs,
            const int* __restrict__ offs, const float* __restrict__ bias,
            const float* __restrict__ gamma, const float* __restrict__ beta,
            const float* __restrict__ mean, const float* __restrict__ var,
            unsigned short* __restrict__ hout,
            const float* __restrict__ gw, const float* __restrict__ gb,
            float* __restrict__ gate, int N) {
  constexpr int VEC = COUT / 64;        // channels per lane: 4 or 8
  constexpr int CAP = 128;
  constexpr int EPAD = 132;
  __shared__ float ehs[4][8][EPAD];
  __shared__ int srcsS[4][CAP];
  int tid = threadIdx.x;
  int w = tid >> 6, l = tid & 63;
  int n = blockIdx.x * 4 + w;
  if (n >= N) return;                   // whole wave exits; no block-level syncs used
  int e0 = offs[n];
  int deg = offs[n + 1] - e0;
  int mcap = deg < CAP ? deg : CAP;
  int hdA = l & 7;                      // head for weight phases
  int eb = l >> 3;                      // edge sub-lane for weight phases
  float aldv = ald[((size_t)n << 3) + hdA];

  // stage srcs into wave-private LDS
  for (int e = l; e < mcap; e += 64) srcsS[w][e] = srcs[e0 + e];

  // phase A: logits -> LDS
  for (int e = eb; e < mcap; e += 8) {
    int s = srcsS[w][e];
    float xx = als[((size_t)(uint32_t)s << 3) + hdA] + aldv;
    ehs[w][hdA][e] = LEAKY(xx);
  }
  // phase B: per-head max (lanes sharing hdA differ in bits 3..5)
  float mx = -1e30f;
  for (int e = eb; e < mcap; e += 8) mx = fmaxf(mx, ehs[w][hdA][e]);
  for (int e = CAP + eb; e < deg; e += 8) {         // overflow (rare)
    int s = srcs[e0 + e];
    mx = fmaxf(mx, LEAKY(als[((size_t)(uint32_t)s << 3) + hdA] + aldv));
  }
  mx = fmaxf(mx, __shfl_xor(mx, 8));
  mx = fmaxf(mx, __shfl_xor(mx, 16));
  mx = fmaxf(mx, __shfl_xor(mx, 32));
  // phase B2: exp in place + denominator
  float dp = 0.f;
  for (int e = eb; e < mcap; e += 8) {
    float ee = __expf(ehs[w][hdA][e] - mx);
    ehs[w][hdA][e] = ee;
    dp += ee;
  }
  for (int e = CAP + eb; e < deg; e += 8) {         // overflow (rare)
    int s = srcs[e0 + e];
    dp += __expf(LEAKY(als[((size_t)(uint32_t)s << 3) + hdA] + aldv) - mx);
  }
  dp += __shfl_xor(dp, 8);
  dp += __shfl_xor(dp, 16);
  dp += __shfl_xor(dp, 32);
  float dinv = 1.f / (dp + 1e-16f);

  // remap to phase-C head (lane owns channels [VEC*l, VEC*l+VEC) -> head = l>>3)
  int hdC = l >> 3;
  float dinvC = __shfl(dinv, hdC);
  float mxC = __shfl(mx, hdC);
  float aldC = __shfl(aldv, hdC);
  const float* eerow = ehs[w][hdC];

  // phase C: wide row gather + weighted accumulate
  float num[VEC] = {};
  int e = 0;
  if (VEC == 4) {
    const uint2* hp = reinterpret_cast<const uint2*>(hpre);  // row = 64 uint2
    // 8-deep batch: all loads issued before accumulation (counted-vmcnt overlap)
    for (; e + 8 <= mcap; e += 8) {
      uint2 wv[8];
#pragma unroll
      for (int j = 0; j < 8; ++j) {
        int s = srcsS[w][e + j];
        wv[j] = hp[((size_t)(uint32_t)s << 6) + l];
      }
#pragma unroll
      for (int j = 0; j < 8; ++j) {
        float ee = eerow[e + j];
        acc2(ee, wv[j].x, num[0], num[1]); acc2(ee, wv[j].y, num[2], num[3]);
      }
    }
    for (; e + 4 <= mcap; e += 4) {
      uint2 wv[4];
#pragma unroll
      for (int j = 0; j < 4; ++j) {
        int s = srcsS[w][e + j];
        wv[j] = hp[((size_t)(uint32_t)s << 6) + l];
      }
#pragma unroll
      for (int j = 0; j < 4; ++j) {
        float ee = eerow[e + j];
        acc2(ee, wv[j].x, num[0], num[1]); acc2(ee, wv[j].y, num[2], num[3]);
      }
    }
    for (; e < mcap; ++e) {
      int s = srcsS[w][e];
      uint2 w0 = hp[((size_t)(uint32_t)s << 6) + l];
      float ee0 = eerow[e];
      acc2(ee0, w0.x, num[0], num[1]); acc2(ee0, w0.y, num[2], num[3]);
    }
    for (; e < deg; ++e) {  // overflow (rare)
      int s = srcs[e0 + e];
      float ee0 = __expf(LEAKY(als[((size_t)(uint32_t)s << 3) + hdC] + aldC) - mxC);
      uint2 w0 = hp[((size_t)(uint32_t)s << 6) + l];
      acc2(ee0, w0.x, num[0], num[1]); acc2(ee0, w0.y, num[2], num[3]);
    }
  } else {
    const uint4* hp = reinterpret_cast<const uint4*>(hpre);  // row = 64 uint4
    for (; e + 4 <= mcap; e += 4) {
      int s0 = srcsS[w][e], s1 = srcsS[w][e + 1];
      int s2 = srcsS[w][e + 2], s3 = srcsS[w][e + 3];
      uint4 w0 = hp[((size_t)(uint32_t)s0 << 6) + l];
      uint4 w1 = hp[((size_t)(uint32_t)s1 << 6) + l];
      uint4 w2 = hp[((size_t)(uint32_t)s2 << 6) + l];
      uint4 w3 = hp[((size_t)(uint32_t)s3 << 6) + l];
      float ee0 = eerow[e], ee1 = eerow[e + 1], ee2 = eerow[e + 2], ee3 = eerow[e + 3];
      acc2(ee0, w0.x, num[0], num[1]); acc2(ee0, w0.y, num[2], num[3]);
      acc2(ee0, w0.z, num[4], num[5]); acc2(ee0, w0.w, num[6], num[7]);
      acc2(ee1, w1.x, num[0], num[1]); acc2(ee1, w1.y, num[2], num[3]);
      acc2(ee1, w1.z, num[4], num[5]); acc2(ee1, w1.w, num[6], num[7]);
      acc2(ee2, w2.x, num[0], num[1]); acc2(ee2, w2.y, num[2], num[3]);
      acc2(ee2, w2.z, num[4], num[5]); acc2(ee2, w2.w, num[6], num[7]);
      acc2(ee3, w3.x, num[0], num[1]); acc2(ee3, w3.y, num[2], num[3]);
      acc2(ee3, w3.z, num[4], num[5]); acc2(ee3, w3.w, num[6], num[7]);
    }
    for (; e < mcap; ++e) {
      int s = srcsS[w][e];
      uint4 w0 = hp[((size_t)(uint32_t)s << 6) + l];
      float ee0 = eerow[e];
      acc2(ee0, w0.x, num[0], num[1]); acc2(ee0, w0.y, num[2], num[3]);
      acc2(ee0, w0.z, num[4], num[5]); acc2(ee0, w0.w, num[6], num[7]);
    }
    for (; e < deg; ++e) {  // overflow (rare)
      int s = srcs[e0 + e];
      float ee0 = __expf(LEAKY(als[((size_t)(uint32_t)s << 3) + hdC] + aldC) - mxC);
      uint4 w0 = hp[((size_t)(uint32_t)s << 6) + l];
      acc2(ee0, w0.x, num[0], num[1]); acc2(ee0, w0.y, num[2], num[3]);
      acc2(ee0, w0.z, num[4], num[5]); acc2(ee0, w0.w, num[6], num[7]);
    }
  }

  // epilogue: bias + BN + ReLU (+ optional fused gate dot)
  unsigned short o[VEC];
  float gp = 0.f;
#pragma unroll
  for (int v = 0; v < VEC; ++v) {
    int c = VEC * l + v;
    float xo = num[v] * dinvC + bias[c];
    xo = (xo - mean[c]) * rsqrtf(var[c] + 1e-5f) * gamma[c] + beta[c];
    xo = fmaxf(xo, 0.f);
    o[v] = f2bf(xo);
    if (GATE) gp += xo * gw[c];
  }
  if (VEC == 4)
    *reinterpret_cast<uint2*>(&hout[(size_t)n * COUT + VEC * l]) = *reinterpret_cast<uint2*>(o);
  else
    *reinterpret_cast<uint4*>(&hout[(size_t)n * COUT + VEC * l]) = *reinterpret_cast<uint4*>(o);
  if (GATE) {
    gp += __shfl_xor(gp, 1);
    gp += __shfl_xor(gp, 2);
    gp += __shfl_xor(gp, 4);
    gp += __shfl_xor(gp, 8);
    gp += __shfl_xor(gp, 16);
    gp += __shfl_xor(gp, 32);
    if (l == 0) gate[n] = gp + gb[0];
  }
}

// ---------------- pooling ----------------
__global__ void __launch_bounds__(256)
poolmax_kernel(const float* __restrict__ gate, const int* __restrict__ gstart,
               float* __restrict__ gmax, float* __restrict__ ginv) {
  int g = blockIdx.x;
  int tid = threadIdx.x;
  int n0 = gstart[g], n1 = gstart[g + 1];
  __shared__ float red[4];
  float mx = -1e30f;
  for (int n = n0 + tid; n < n1; n += 256) mx = fmaxf(mx, gate[n]);
#pragma unroll
  for (int o = 32; o >= 1; o >>= 1) mx = fmaxf(mx, __shfl_xor(mx, o));
  if ((tid & 63) == 0) red[tid >> 6] = mx;
  __syncthreads();
  mx = fmaxf(fmaxf(red[0], red[1]), fmaxf(red[2], red[3]));
  __syncthreads();
  float sm = 0.f;
  for (int n = n0 + tid; n < n1; n += 256) sm += __expf(gate[n] - mx);
#pragma unroll
  for (int o = 32; o >= 1; o >>= 1) sm += __shfl_xor(sm, o);
  if ((tid & 63) == 0) red[tid >> 6] = sm;
  __syncthreads();
  if (tid == 0) {
    sm = red[0] + red[1] + red[2] + red[3];
    gmax[g] = mx;
    ginv[g] = 1.f / (sm + 1e-16f);
  }
}

__global__ void __launch_bounds__(256)
poolsum_kernel(const float* __restrict__ gate, const unsigned short* __restrict__ h3,
               const int* __restrict__ batch, const float* __restrict__ gmax,
               const float* __restrict__ ginv, float* __restrict__ pooled, int N) {
  int tid = threadIdx.x;                 // channel 0..255
  int nbase = blockIdx.x * 64;
  float acc = 0.f;
  int cur = batch[nbase];
  for (int i = 0; i < 64; ++i) {
    int n = nbase + i;
    if (n >= N) break;
    int b = batch[n];
    if (b != cur) {
      atomicAdd(&pooled[cur * 256 + tid], acc);
      acc = 0.f;
      cur = b;
    }
    float w = __expf(gate[n] - gmax[b]) * ginv[b];
    acc += w * bf2f(h3[(size_t)n * 256 + tid]);
  }
  atomicAdd(&pooled[cur * 256 + tid], acc);
}

__global__ void __launch_bounds__(64)
head_kernel(const float* __restrict__ pooled, const float* __restrict__ f1w,
            const float* __restrict__ f1b, const float* __restrict__ f2w,
            const float* __restrict__ f2b, float* __restrict__ out) {
  int g = blockIdx.x;
  int l = threadIdx.x;  // 64 lanes
  float p[4];
#pragma unroll
  for (int v = 0; v < 4; ++v) p[v] = pooled[g * 256 + l * 4 + v];
  float acc = 0.f;
#pragma unroll
  for (int j = 0; j < 16; ++j) {
    float s = 0.f;
#pragma unroll
    for (int v = 0; v < 4; ++v) s += p[v] * f1w[(l * 4 + v) * 16 + j];
#pragma unroll
    for (int o = 32; o >= 1; o >>= 1) s += __shfl_xor(s, o);
    float hj = fmaxf(s + f1b[j], 0.f);
    acc += hj * f2w[j];
  }
  if (l == 0) out[g] = acc + f2b[0];
}

// ---------------- launch ----------------
extern "C" void kernel_launch(void* const* d_in, const int* in_sizes, int n_in,
                              void* d_out, int out_size, void* d_ws, size_t ws_size,
                              hipStream_t stream) {
  const float* x    = (const float*)d_in[0];
  const int*   ei   = (const int*)d_in[1];
  const int*   batch= (const int*)d_in[2];
  const float* W1   = (const float*)d_in[3];
  const float* a1s  = (const float*)d_in[4];
  const float* a1d  = (const float*)d_in[5];
  const float* b1   = (const float*)d_in[6];
  const float* g1   = (const float*)d_in[7];
  const float* be1  = (const float*)d_in[8];
  const float* m1   = (const float*)d_in[9];
  const float* v1   = (const float*)d_in[10];
  const float* W2   = (const float*)d_in[11];
  const float* a2s  = (const float*)d_in[12];
  const float* a2d  = (const float*)d_in[13];
  const float* b2   = (const float*)d_in[14];
  const float* g2   = (const float*)d_in[15];
  const float* be2  = (const float*)d_in[16];
  const float* m2   = (const float*)d_in[17];
  const float* v2   = (const float*)d_in[18];
  const float* W3   = (const float*)d_in[19];
  const float* a3s  = (const float*)d_in[20];
  const float* a3d  = (const float*)d_in[21];
  const float* b3   = (const float*)d_in[22];
  const float* g3   = (const float*)d_in[23];
  const float* be3  = (const float*)d_in[24];
  const float* m3   = (const float*)d_in[25];
  const float* v3   = (const float*)d_in[26];
  const float* gw   = (const float*)d_in[27];
  const float* gb   = (const float*)d_in[28];
  const float* f1w  = (const float*)d_in[29];
  const float* f1b  = (const float*)d_in[30];
  const float* f2w  = (const float*)d_in[31];
  const float* f2b  = (const float*)d_in[32];

  int N = in_sizes[2];        // 50000
  int E = in_sizes[1] / 2;    // 800000
  const int* esrc = ei;
  const int* edst = ei + E;

  char* ws = (char*)d_ws;
  size_t off = 0;
  auto take = [&](size_t bytes) -> void* {
    void* p = ws + off;
    off += (bytes + 255) & ~(size_t)255;
    return p;
  };
  unsigned short* XBF  = (unsigned short*)take((size_t)N * 128 * 2);
  unsigned short* WT1  = (unsigned short*)take((size_t)256 * 128 * 2);
  unsigned short* WT2  = (unsigned short*)take((size_t)512 * 256 * 2);
  unsigned short* WT3  = (unsigned short*)take((size_t)256 * 512 * 2);
  unsigned short* HPRE = (unsigned short*)take((size_t)N * 512 * 2);
  unsigned short* HB   = (unsigned short*)take((size_t)N * 512 * 2);
  float* ALS   = (float*)take((size_t)N * 8 * 4);
  float* ALD   = (float*)take((size_t)N * 8 * 4);
  int*   CNT   = (int*)take((size_t)N * 4);
  int*   OFFS  = (int*)take((size_t)(N + 1) * 4);
  int*   FILL  = (int*)take((size_t)N * 4);
  int*   EXC   = (int*)take((size_t)N * 4);
  int*   PSUM  = (int*)take(256 * 4);
  int*   SRCS  = (int*)take((size_t)(E + N) * 4);
  float* GATE  = (float*)take((size_t)N * 4);
  int*   GST   = (int*)take(65 * 4);
  float* POOLED= (float*)take(64 * 256 * 4);
  float* GMAX  = (float*)take(64 * 4);
  float* GINV  = (float*)take(64 * 4);
  (void)ws_size; (void)n_in; (void)out_size;

  // ---- conversions + CSR build ----
  f2bf_kernel<<<(N * 128 / 4 + 255) / 256, 256, 0, stream>>>(x, XBF, N * 128 / 4);
  wt3_kernel<<<(294912 + 255) / 256, 256, 0, stream>>>(W1, W2, W3, WT1, WT2, WT3);

  hipMemsetAsync(CNT, 0, (size_t)N * 4, stream);
  hipMemsetAsync(POOLED, 0, 64 * 256 * 4, stream);
  int tE = E + N;
  count_kernel<<<(tE + 255) / 256, 256, 0, stream>>>(edst, CNT, E, N);
  int nb = (N + 255) / 256;
  scan1_kernel<<<nb, 256, 0, stream>>>(CNT, EXC, PSUM, N);
  scan2_kernel<<<1, 256, 0, stream>>>(PSUM, OFFS, nb, N);
  scan3_kernel<<<nb, 256, 0, stream>>>(EXC, PSUM, OFFS, FILL, N);
  fill_kernel<<<(tE + 255) / 256, 256, 0, stream>>>(esrc, edst, FILL, SRCS, E, N);
  starts_kernel<<<(N + 255) / 256, 256, 0, stream>>>(batch, GST, N, 64);

  int mgrid = (N + 127) / 128;
  int agrid = (N + 3) / 4;

  // ---- layer 1: 128 -> 8x32 ----
  {
    gemm_bf16<<<mgrid * 2, 256, 0, stream>>>(XBF, WT1, HPRE, N, 128, 256, 1);
    al2_kernel<256><<<agrid, 256, 0, stream>>>(HPRE, a1s, a1d, ALS, ALD, N);
    agg4_kernel<256, false><<<agrid, 256, 0, stream>>>(HPRE, ALS, ALD, SRCS, OFFS,
                                                       b1, g1, be1, m1, v1, HB,
                                                       nullptr, nullptr, nullptr, N);
  }
  // ---- layer 2: 256 -> 8x64 ----
  {
    gemm_bf16<<<mgrid * 4, 256, 0, stream>>>(HB, WT2, HPRE, N, 256, 512, 2);
    al2_kernel<512><<<agrid, 256, 0, stream>>>(HPRE, a2s, a2d, ALS, ALD, N);
    agg4_kernel<512, false><<<agrid, 256, 0, stream>>>(HPRE, ALS, ALD, SRCS, OFFS,
                                                       b2, g2, be2, m2, v2, HB,
                                                       nullptr, nullptr, nullptr, N);
  }
  // ---- layer 3: 512 -> 8x32, gate fused ----
  {
    gemm_bf16<<<mgrid * 2, 256, 0, stream>>>(HB, WT3, HPRE, N, 512, 256, 1);
    al2_kernel<256><<<agrid, 256, 0, stream>>>(HPRE, a3s, a3d, ALS, ALD, N);
    agg4_kernel<256, true><<<agrid, 256, 0, stream>>>(HPRE, ALS, ALD, SRCS, OFFS,
                                                      b3, g3, be3, m3, v3, HB,
                                                      gw, gb, GATE, N);
  }

  // ---- global attention pooling + MLP head ----
  poolmax_kernel<<<64, 256, 0, stream>>>(GATE, GST, GMAX, GINV);
  poolsum_kernel<<<(N + 63) / 64, 256, 0, stream>>>(GATE, HB, batch, GMAX, GINV, POOLED, N);
  head_kernel<<<64, 64, 0, stream>>>(POOLED, f1w, f1b, f2w, f2b, (float*)d_out);
}